// Round 12
// baseline (382.153 us; speedup 1.0000x reference)
//
#include <hip/hip_runtime.h>
#include <hip/hip_bf16.h>
#include <math.h>

#define BSHIFT 7                 // 128 nodes per bucket
#define NBUCK(N) (((N) + 127) >> 7)
#define TILE 2048                // R12: 1612 part blocks (~4x waves); amp held
                                 // at ~1x by per-XCD windows (R11-proven)
#define CAP 5632                 // csr per bucket = 8 windows x 704 (exact)
#define CAPXD 704                // gbufD: per (bucket,XCD) window (mean 528, 7.6 sigma)
#define CAPS 2040                // gbufS: per (bucket,XCD) window (mean 528)
#define NXCD 8

typedef short bf16x8 __attribute__((ext_vector_type(8)));
typedef float f32x16 __attribute__((ext_vector_type(16)));

// ---- bf16 helpers ---------------------------------------------------------
__device__ __forceinline__ unsigned short f2bf(float f) {
    unsigned u = __float_as_uint(f);
    u += 0x7fffu + ((u >> 16) & 1u);      // RNE
    return (unsigned short)(u >> 16);
}
__device__ __forceinline__ unsigned packbf2(float lo, float hi) {
    return (unsigned)f2bf(lo) | ((unsigned)f2bf(hi) << 16);
}
__device__ __forceinline__ float bf_lo(unsigned u) { return __uint_as_float(u << 16); }
__device__ __forceinline__ float bf_hi(unsigned u) { return __uint_as_float(u & 0xffff0000u); }

__device__ __forceinline__ int xcc_id() {
    int x;
    asm volatile("s_getreg_b32 %0, hwreg(HW_REG_XCC_ID)" : "=s"(x));
    return x & (NXCD - 1);
}

// ---- pg: part (blocks < PB) fused with gemm1 (blocks >= PB) ---------------
// R12: part at TILE=2048 (1612 blocks, ~25 waves/CU vs 6). Prior occupancy
// attempts failed via (R1/R2) VGPR-16 spill and (R3) write amp at short
// segments; both fixed: dv[8] register-healthy loop + per-XCD windows on
// gbufD (bucket-major: (b*8+xcd)*704, so a bucket's 8 windows = contiguous
// 22.5KB = CAP) and gbufS (R11's proven form).
__global__ __launch_bounds__(256) void pg_kernel(
    const int* __restrict__ src, const int* __restrict__ dst,
    int* __restrict__ gcurD, int* __restrict__ gcurS,
    int* __restrict__ gbufD, unsigned char* __restrict__ gbufS,
    const float* __restrict__ feat, const float* __restrict__ W1,
    unsigned short* __restrict__ h1, int E, int K, int PB, int N) {
    __shared__ char smem[16896];   // max(part 12.8 KB, gemm W1t 16.9 KB)
    const int t = threadIdx.x;

    if (blockIdx.x < PB) {
        // ---------------- part body ----------------
        int* cD = (int*)smem;
        int* bD = cD + 800;
        int* cS = bD + 800;
        int* bS = cS + 800;        // 3200 ints = 12.8 KB
        const int tile = blockIdx.x * TILE;
        const int vx = xcc_id();
        for (int i = t; i < K; i += 256) { cD[i] = 0; cS[i] = 0; }
        __syncthreads();

        int dv[8];
        #pragma unroll
        for (int i = 0; i < 8; ++i) {
            const int e = tile + i * 256 + t;
            dv[i] = (e < E) ? dst[e] : -1;
            if (dv[i] >= 0) {
                atomicAdd(&cD[dv[i] >> BSHIFT], 1);
                atomicAdd(&cS[src[e] >> BSHIFT], 1);
            }
        }
        __syncthreads();
        for (int i = t; i < K; i += 256) {
            int c = cD[i];
            bD[i] = (c ? atomicAdd(&gcurD[i * NXCD + vx], c) : 0) + (i * NXCD + vx) * CAPXD;
            cD[i] = 0;
            c = cS[i];
            bS[i] = (c ? atomicAdd(&gcurS[vx * K + i], c) : 0) + (vx * K + i) * CAPS;
            cS[i] = 0;
        }
        __syncthreads();
        #pragma unroll
        for (int i = 0; i < 8; ++i) {
            if (dv[i] >= 0) {
                const int e = tile + i * 256 + t;
                const int sv = src[e];
                const int b1 = dv[i] >> BSHIFT;
                const int p1 = bD[b1] + atomicAdd(&cD[b1], 1);
                gbufD[p1] = ((dv[i] & 127) << 17) | sv;
                const int b2 = sv >> BSHIFT;
                const int p2 = bS[b2] + atomicAdd(&cS[b2], 1);
                gbufS[p2] = (unsigned char)(sv & 127);
            }
        }
    } else {
        // ---------------- gemm1 body (unscaled h1) -------------------------
        short* W1t = (short*)smem;     // W1t[c][k] = bf16(W1[k][c]), stride 264
        for (int i = t; i < 8192; i += 256) {
            const int k = i >> 5, c = i & 31;
            W1t[c * 264 + k] = (short)f2bf(W1[i]);
        }
        __syncthreads();

        const int l  = t & 63;
        const int wv = t >> 6;
        const int base = (blockIdx.x - PB) * 128 + wv * 32;
        const int m  = l & 31;
        const int kh = (l >> 5) << 3;
        int r = base + m;
        if (r >= N) r = N - 1;
        const float* fr = feat + (size_t)r * 256 + kh;
        const short* wr = &W1t[m * 264 + kh];

        f32x16 acc;
        #pragma unroll
        for (int i = 0; i < 16; ++i) acc[i] = 0.f;

        #pragma unroll
        for (int kb = 0; kb < 16; ++kb) {
            const float4 f0 = *(const float4*)(fr + kb * 16);
            const float4 f1 = *(const float4*)(fr + kb * 16 + 4);
            bf16x8 a;
            a[0] = (short)f2bf(f0.x); a[1] = (short)f2bf(f0.y);
            a[2] = (short)f2bf(f0.z); a[3] = (short)f2bf(f0.w);
            a[4] = (short)f2bf(f1.x); a[5] = (short)f2bf(f1.y);
            a[6] = (short)f2bf(f1.z); a[7] = (short)f2bf(f1.w);
            const bf16x8 b = *(const bf16x8*)(wr + kb * 16);
            acc = __builtin_amdgcn_mfma_f32_32x32x16_bf16(a, b, acc, 0, 0, 0);
        }

        const int rbase = base + ((l >> 5) << 2);
        #pragma unroll
        for (int reg = 0; reg < 16; ++reg) {
            const int row = rbase + (reg & 3) + ((reg >> 2) << 3);
            if (row < N)
                h1[(size_t)row * 32 + m] = f2bf(acc[reg]);
        }
    }
}

// ---- fillS: outdeg -> nsrc, AND pre-scale this bucket's h1 rows by nsrc ---
__global__ __launch_bounds__(256) void fillS_kernel(
    const int* __restrict__ cntS, const unsigned char* __restrict__ gbufS,
    float* __restrict__ nsrc, unsigned* __restrict__ h1, int N, int K) {
    __shared__ int cnt[128];
    __shared__ float sns[128];
    const int t = threadIdx.x;
    const int b = blockIdx.x;
    if (t < 128) cnt[t] = 0;
    __syncthreads();
    for (int x = 0; x < NXCD; ++x) {
        const int seg = x * K + b;
        const int bs = seg * CAPS;
        const int be = bs + min(cntS[seg], CAPS);
        for (int idx = bs + t; idx < be; idx += 256)
            atomicAdd(&cnt[gbufS[idx]], 1);
    }
    __syncthreads();
    if (t < 128) {
        const float v = rsqrtf((float)cnt[t]);   // self-loops => deg>=1
        sns[t] = v;
        const int n = (b << BSHIFT) + t;
        if (n < N) nsrc[n] = v;
    }
    __syncthreads();
    // scale h1 rows in place: 2 threads/node x 8 u32 (row = 16 u32 = 64 B)
    const int node = t >> 1;
    const int n = (b << BSHIFT) + node;
    if (n < N) {
        const float ns = sns[node];
        unsigned* row = h1 + (size_t)n * 16 + (t & 1) * 8;
        uint4 q0 = *(uint4*)row;
        uint4 q1 = *(uint4*)(row + 4);
        q0.x = packbf2(bf_lo(q0.x) * ns, bf_hi(q0.x) * ns);
        q0.y = packbf2(bf_lo(q0.y) * ns, bf_hi(q0.y) * ns);
        q0.z = packbf2(bf_lo(q0.z) * ns, bf_hi(q0.z) * ns);
        q0.w = packbf2(bf_lo(q0.w) * ns, bf_hi(q0.w) * ns);
        q1.x = packbf2(bf_lo(q1.x) * ns, bf_hi(q1.x) * ns);
        q1.y = packbf2(bf_lo(q1.y) * ns, bf_hi(q1.y) * ns);
        q1.z = packbf2(bf_lo(q1.z) * ns, bf_hi(q1.z) * ns);
        q1.w = packbf2(bf_lo(q1.w) * ns, bf_hi(q1.w) * ns);
        *(uint4*)row = q0;
        *(uint4*)(row + 4) = q1;
    }
}

// ---- fda1: fillD + agg1 fused, one 512-thread block per dst-bucket --------
// Reads the bucket's 8 per-XCD windows (its contiguous 22.5KB region),
// LDS sort, CSR dumped in place at region start (b*CAP), gather 8 lanes/node.
__global__ __launch_bounds__(512) void fda1_kernel(
    const int* __restrict__ cntD, int* __restrict__ gbufD,
    const unsigned* __restrict__ h1, const float* __restrict__ nsrc,
    const float* __restrict__ b1, int* __restrict__ rowstart,
    int* __restrict__ indeg, float* __restrict__ ndst,
    unsigned* __restrict__ x1s, int N, int K) {
    __shared__ int lraw[CAP];          // 22.5 KB
    __shared__ int lcsr[CAP];          // 22.5 KB
    __shared__ int cnt[128], sc[128], cur[128];
    __shared__ int scnt[NXCD];
    __shared__ float sb1[32];
    const int t = threadIdx.x;
    const int b = blockIdx.x;
    if (t < 128) cnt[t] = 0;
    if (t < NXCD) scnt[t] = min(cntD[b * NXCD + t], CAPXD);
    if (t >= 128 && t < 160) sb1[t - 128] = b1[t - 128];
    __syncthreads();

    int soff[NXCD];
    {
        int acc = 0;
        #pragma unroll
        for (int x = 0; x < NXCD; ++x) { soff[x] = acc; acc += scnt[x]; }
    }
    const int total = soff[NXCD - 1] + scnt[NXCD - 1];

    for (int x = 0; x < NXCD; ++x) {
        const int bs = (b * NXCD + x) * CAPXD;
        const int c0 = scnt[x], o0 = soff[x];
        for (int i = t; i < c0; i += 512) {
            const int v = gbufD[bs + i];
            lraw[o0 + i] = v;
            atomicAdd(&cnt[v >> 17], 1);
        }
    }
    __syncthreads();
    if (t < 128) sc[t] = cnt[t];
    __syncthreads();
    for (int off = 1; off < 128; off <<= 1) {
        int x = (t < 128 && t >= off) ? sc[t - off] : 0;
        __syncthreads();
        if (t < 128) sc[t] += x;
        __syncthreads();
    }
    if (t < 128) {
        const int deg = cnt[t];
        cur[t] = sc[t] - deg;          // bucket-local
        const int n = (b << BSHIFT) + t;
        if (n < N) {
            rowstart[n] = b * CAP + sc[t] - deg;
            indeg[n] = deg;
            ndst[n] = rsqrtf((float)deg);   // self-loops => deg >= 1
        }
    }
    __syncthreads();
    for (int i = t; i < total; i += 512) {
        const int v = lraw[i];
        const int pos = atomicAdd(&cur[v >> 17], 1);
        lcsr[pos] = v & 131071;
    }
    __syncthreads();
    // dump sorted CSR over this bucket's contiguous region (all reads done)
    for (int i = t; i < total; i += 512) gbufD[b * CAP + i] = lcsr[i];

    // ---- agg1 from LDS csr: 8 lanes/node, 2 passes of 64 nodes ----
    const int c  = t & 3;
    const int eg = (t >> 2) & 1;
    const uint4* H = (const uint4*)h1;
    for (int half = 0; half < 2; ++half) {
        const int node = (t >> 3) + half * 64;
        const int n = (b << BSHIFT) + node;
        if (n >= N) continue;
        const int deg = cnt[node];
        const int re = sc[node];
        const int rs = re - deg;
        const int n8 = deg >> 3;
        float a0=0.f,a1=0.f,a2=0.f,a3=0.f,a4=0.f,a5=0.f,a6=0.f,a7=0.f;
        float d0=0.f,d1=0.f,d2=0.f,d3=0.f,d4=0.f,d5=0.f,d6=0.f,d7=0.f;
        for (int i = 0; i < n8; ++i) {
            const int k0 = rs + i * 8 + eg * 4;
            const int s0 = lcsr[k0],     s1 = lcsr[k0 + 1];
            const int s2 = lcsr[k0 + 2], s3 = lcsr[k0 + 3];
            const uint4 q0 = H[(size_t)s0 * 4 + c];
            const uint4 q1 = H[(size_t)s1 * 4 + c];
            const uint4 q2 = H[(size_t)s2 * 4 + c];
            const uint4 q3 = H[(size_t)s3 * 4 + c];
            a0 += bf_lo(q0.x); a1 += bf_hi(q0.x);
            a2 += bf_lo(q0.y); a3 += bf_hi(q0.y);
            a4 += bf_lo(q0.z); a5 += bf_hi(q0.z);
            a6 += bf_lo(q0.w); a7 += bf_hi(q0.w);
            d0 += bf_lo(q1.x); d1 += bf_hi(q1.x);
            d2 += bf_lo(q1.y); d3 += bf_hi(q1.y);
            d4 += bf_lo(q1.z); d5 += bf_hi(q1.z);
            d6 += bf_lo(q1.w); d7 += bf_hi(q1.w);
            a0 += bf_lo(q2.x); a1 += bf_hi(q2.x);
            a2 += bf_lo(q2.y); a3 += bf_hi(q2.y);
            a4 += bf_lo(q2.z); a5 += bf_hi(q2.z);
            a6 += bf_lo(q2.w); a7 += bf_hi(q2.w);
            d0 += bf_lo(q3.x); d1 += bf_hi(q3.x);
            d2 += bf_lo(q3.y); d3 += bf_hi(q3.y);
            d4 += bf_lo(q3.z); d5 += bf_hi(q3.z);
            d6 += bf_lo(q3.w); d7 += bf_hi(q3.w);
        }
        for (int k = rs + n8 * 8 + eg; k < re; k += 2) {
            const int s0 = lcsr[k];
            const uint4 q0 = H[(size_t)s0 * 4 + c];
            a0 += bf_lo(q0.x); a1 += bf_hi(q0.x);
            a2 += bf_lo(q0.y); a3 += bf_hi(q0.y);
            a4 += bf_lo(q0.z); a5 += bf_hi(q0.z);
            a6 += bf_lo(q0.w); a7 += bf_hi(q0.w);
        }
        a0 += d0; a1 += d1; a2 += d2; a3 += d3;
        a4 += d4; a5 += d5; a6 += d6; a7 += d7;
        // merge the two edge-groups (lanes t and t^4)
        a0 += __shfl_xor(a0, 4, 64); a1 += __shfl_xor(a1, 4, 64);
        a2 += __shfl_xor(a2, 4, 64); a3 += __shfl_xor(a3, 4, 64);
        a4 += __shfl_xor(a4, 4, 64); a5 += __shfl_xor(a5, 4, 64);
        a6 += __shfl_xor(a6, 4, 64); a7 += __shfl_xor(a7, 4, 64);
        if (eg == 0) {
            const float nd = rsqrtf((float)deg);
            const float ns = nsrc[n];
            const float* bb = sb1 + c * 8;
            float x0 = fmaxf(a0 * nd + bb[0], 0.f) * ns;
            float x1 = fmaxf(a1 * nd + bb[1], 0.f) * ns;
            float x2 = fmaxf(a2 * nd + bb[2], 0.f) * ns;
            float x3 = fmaxf(a3 * nd + bb[3], 0.f) * ns;
            float x4 = fmaxf(a4 * nd + bb[4], 0.f) * ns;
            float x5 = fmaxf(a5 * nd + bb[5], 0.f) * ns;
            float x6 = fmaxf(a6 * nd + bb[6], 0.f) * ns;
            float x7 = fmaxf(a7 * nd + bb[7], 0.f) * ns;
            uint4 o;
            o.x = packbf2(x0, x1); o.y = packbf2(x2, x3);
            o.z = packbf2(x4, x5); o.w = packbf2(x6, x7);
            ((uint4*)x1s)[(size_t)n * 4 + c] = o;
        }
    }
}

// ---- agg2+final fused: 8 lanes/node edge-split, 32 nodes/block ------------
__global__ __launch_bounds__(256) void agg2f_kernel(
    const int* __restrict__ csr_src, const int* __restrict__ rowstart,
    const int* __restrict__ indeg, const unsigned* __restrict__ x1s,
    const float* __restrict__ ndst, const float* __restrict__ W2,
    const float* __restrict__ b2, float* __restrict__ out, int N) {
    __shared__ float sW2[32 * 40];
    __shared__ float sb2[40];
    const int t = threadIdx.x;
    for (int i = t; i < 1280; i += 256) sW2[i] = W2[i];
    if (t < 40) sb2[t] = b2[t];
    __syncthreads();
    const int n = blockIdx.x * 32 + (t >> 3);
    if (n >= N) return;
    const int c  = t & 3;
    const int eg = (t >> 2) & 1;
    const int rs = rowstart[n];
    const int deg = indeg[n];
    const int re = rs + deg;
    const int n8 = deg >> 3;
    float a0=0.f,a1=0.f,a2=0.f,a3=0.f,a4=0.f,a5=0.f,a6=0.f,a7=0.f;
    float d0=0.f,d1=0.f,d2=0.f,d3=0.f,d4=0.f,d5=0.f,d6=0.f,d7=0.f;
    const uint4* H = (const uint4*)x1s;
    for (int i = 0; i < n8; ++i) {
        const int k0 = rs + i * 8 + eg * 4;
        const int s0 = csr_src[k0],     s1 = csr_src[k0 + 1];
        const int s2 = csr_src[k0 + 2], s3 = csr_src[k0 + 3];
        const uint4 q0 = H[(size_t)s0 * 4 + c];
        const uint4 q1 = H[(size_t)s1 * 4 + c];
        const uint4 q2 = H[(size_t)s2 * 4 + c];
        const uint4 q3 = H[(size_t)s3 * 4 + c];
        a0 += bf_lo(q0.x); a1 += bf_hi(q0.x);
        a2 += bf_lo(q0.y); a3 += bf_hi(q0.y);
        a4 += bf_lo(q0.z); a5 += bf_hi(q0.z);
        a6 += bf_lo(q0.w); a7 += bf_hi(q0.w);
        d0 += bf_lo(q1.x); d1 += bf_hi(q1.x);
        d2 += bf_lo(q1.y); d3 += bf_hi(q1.y);
        d4 += bf_lo(q1.z); d5 += bf_hi(q1.z);
        d6 += bf_lo(q1.w); d7 += bf_hi(q1.w);
        a0 += bf_lo(q2.x); a1 += bf_hi(q2.x);
        a2 += bf_lo(q2.y); a3 += bf_hi(q2.y);
        a4 += bf_lo(q2.z); a5 += bf_hi(q2.z);
        a6 += bf_lo(q2.w); a7 += bf_hi(q2.w);
        d0 += bf_lo(q3.x); d1 += bf_hi(q3.x);
        d2 += bf_lo(q3.y); d3 += bf_hi(q3.y);
        d4 += bf_lo(q3.z); d5 += bf_hi(q3.z);
        d6 += bf_lo(q3.w); d7 += bf_hi(q3.w);
    }
    for (int k = rs + n8 * 8 + eg; k < re; k += 2) {
        const int s0 = csr_src[k];
        const uint4 q0 = H[(size_t)s0 * 4 + c];
        a0 += bf_lo(q0.x); a1 += bf_hi(q0.x);
        a2 += bf_lo(q0.y); a3 += bf_hi(q0.y);
        a4 += bf_lo(q0.z); a5 += bf_hi(q0.z);
        a6 += bf_lo(q0.w); a7 += bf_hi(q0.w);
    }
    a0 += d0; a1 += d1; a2 += d2; a3 += d3;
    a4 += d4; a5 += d5; a6 += d6; a7 += d7;
    a0 += __shfl_xor(a0, 4, 64); a1 += __shfl_xor(a1, 4, 64);
    a2 += __shfl_xor(a2, 4, 64); a3 += __shfl_xor(a3, 4, 64);
    a4 += __shfl_xor(a4, 4, 64); a5 += __shfl_xor(a5, 4, 64);
    a6 += __shfl_xor(a6, 4, 64); a7 += __shfl_xor(a7, 4, 64);
    const float nd = ndst[n];
    const float v0 = a0 * nd, v1 = a1 * nd, v2 = a2 * nd, v3 = a3 * nd;
    const float v4 = a4 * nd, v5 = a5 * nd, v6 = a6 * nd, v7 = a7 * nd;

    // lane j of the node's 8-lane group computes logits j*5 .. j*5+4.
    const int j = t & 7;
    float z[5];
    #pragma unroll
    for (int u = 0; u < 5; ++u) z[u] = sb2[j * 5 + u];
    const int gbase = (t & 63) & ~7;      // wave-lane base of this node's group
    #pragma unroll
    for (int cc = 0; cc < 4; ++cc) {
        const int sl = gbase + cc;        // lane holding channel-quarter cc
        const float w0 = __shfl(v0, sl, 64);
        const float w1 = __shfl(v1, sl, 64);
        const float w2 = __shfl(v2, sl, 64);
        const float w3 = __shfl(v3, sl, 64);
        const float w4 = __shfl(v4, sl, 64);
        const float w5 = __shfl(v5, sl, 64);
        const float w6 = __shfl(v6, sl, 64);
        const float w7 = __shfl(v7, sl, 64);
        const float* Wr = &sW2[(cc * 8) * 40 + j * 5];
        #pragma unroll
        for (int u = 0; u < 5; ++u) {
            z[u] += w0 * Wr[u]       + w1 * Wr[40 + u]  + w2 * Wr[80 + u]  + w3 * Wr[120 + u]
                  + w4 * Wr[160 + u] + w5 * Wr[200 + u] + w6 * Wr[240 + u] + w7 * Wr[280 + u];
        }
    }
    float m = z[0];
    #pragma unroll
    for (int u = 1; u < 5; ++u) m = fmaxf(m, z[u]);
    m = fmaxf(m, __shfl_xor(m, 1, 64));
    m = fmaxf(m, __shfl_xor(m, 2, 64));
    m = fmaxf(m, __shfl_xor(m, 4, 64));
    float s = 0.f;
    #pragma unroll
    for (int u = 0; u < 5; ++u) s += __expf(z[u] - m);
    s += __shfl_xor(s, 1, 64);
    s += __shfl_xor(s, 2, 64);
    s += __shfl_xor(s, 4, 64);
    const float ls = __logf(s);
    float* op = out + (size_t)n * 40 + j * 5;
    #pragma unroll
    for (int u = 0; u < 5; ++u) op[u] = z[u] - m - ls;
}

extern "C" void kernel_launch(void* const* d_in, const int* in_sizes, int n_in,
                              void* d_out, int out_size, void* d_ws, size_t ws_size,
                              hipStream_t stream) {
    const float* feat = (const float*)d_in[0];
    const int*   src  = (const int*)d_in[1];
    const int*   dst  = (const int*)d_in[2];
    const float* W1   = (const float*)d_in[3];
    const float* b1   = (const float*)d_in[4];
    const float* W2   = (const float*)d_in[5];
    const float* b2   = (const float*)d_in[6];
    float* out = (float*)d_out;

    const int N = in_sizes[0] / 256;   // 100000
    const int E = in_sizes[1];         // 3300000
    const int K = NBUCK(N);            // 782 buckets of 128 nodes

    // layout (same ~44.5 MB as R11; gbufD total unchanged: K*8*704 = K*CAP).
    //   gbufD bucket-major per-XCD windows; csr dumped in place per bucket.
    //   gbufS (NXCD*K*CAPS = 12.76 MB) -> over dead a2 region (12.8 MB).
    char* p = (char*)d_ws;
    float* nsrc = (float*)p;                 p += (size_t)N * 4;        // 400 KB
    float* ndst = (float*)p;                 p += (size_t)N * 4;
    unsigned* h1  = (unsigned*)p;            p += (size_t)N * 64;       // 6.4 MB
    unsigned* x1s = (unsigned*)p;            p += (size_t)N * 64;       // 6.4 MB
    char* a2dead = (char*)p;                 p += (size_t)N * 128;      // 12.8 MB
    int* rowstart = (int*)p;                 p += (size_t)N * 4;
    int* indeg_i  = (int*)p;                 p += (size_t)N * 4;
    int* gcurD    = (int*)p;                 p += (size_t)800 * NXCD * 4;
    int* gcurS    = (int*)p;                 p += (size_t)NXCD * 800 * 4;
    int* gbufD    = (int*)p;                 p += (size_t)K * CAP * 4;  // 17.6 MB, becomes csr
    unsigned char* gbufS = (unsigned char*)a2dead;   // 12.76 MB over dead a2

    hipMemsetAsync(gcurD, 0, sizeof(int) * (size_t)800 * NXCD * 2, stream);

    const int PB = (E + TILE - 1) / TILE;      // 1612 partition blocks
    const int GB = (N + 127) / 128;            // 782 gemm blocks

    pg_kernel<<<PB + GB, 256, 0, stream>>>(src, dst, gcurD, gcurS, gbufD, gbufS,
                                           feat, W1, (unsigned short*)h1, E, K, PB, N);
    fillS_kernel<<<K, 256, 0, stream>>>(gcurS, gbufS, nsrc, h1, N, K);
    fda1_kernel<<<K, 512, 0, stream>>>(gcurD, gbufD, h1, nsrc, b1,
                                       rowstart, indeg_i, ndst, x1s, N, K);
    agg2f_kernel<<<(N + 31) / 32, 256, 0, stream>>>(gbufD, rowstart, indeg_i, x1s, ndst, W2, b2, out, N);
}

// Round 13
// 338.579 us; speedup vs baseline: 1.1287x; 1.1287x over previous
//
#include <hip/hip_runtime.h>
#include <hip/hip_bf16.h>
#include <math.h>

#define BSHIFT 7                 // 128 nodes per bucket
#define NBUCK(N) (((N) + 127) >> 7)
#define TILE 8192                // R12 closed occupancy: TILE=8192 is final
#define CAP 5632                 // gbufD/csr: max edges/bucket (mean 4224, ~21 sigma)
#define CAPS 2040                // gbufS: max edges/(bucket,XCD) window
#define NXCD 8

typedef short bf16x8 __attribute__((ext_vector_type(8)));
typedef float f32x16 __attribute__((ext_vector_type(16)));

// ---- bf16 helpers ---------------------------------------------------------
__device__ __forceinline__ unsigned short f2bf(float f) {
    unsigned u = __float_as_uint(f);
    u += 0x7fffu + ((u >> 16) & 1u);      // RNE
    return (unsigned short)(u >> 16);
}
__device__ __forceinline__ unsigned packbf2(float lo, float hi) {
    return (unsigned)f2bf(lo) | ((unsigned)f2bf(hi) << 16);
}
__device__ __forceinline__ float bf_lo(unsigned u) { return __uint_as_float(u << 16); }
__device__ __forceinline__ float bf_hi(unsigned u) { return __uint_as_float(u & 0xffff0000u); }

__device__ __forceinline__ int xcc_id() {
    int x;
    asm volatile("s_getreg_b32 %0, hwreg(HW_REG_XCC_ID)" : "=s"(x));
    return x & (NXCD - 1);
}

// ---- pg: part (blocks < PB) fused with gemm1 (blocks >= PB) ---------------
// EXACT R11 form (342.4 us total best). Occupancy closed as a lever (R12:
// 73% occ was SLOWER -- TILE=2048 quadruples reservation atomics into the
// R9-measured atomic-rate wall). gbufS per-XCD windows (R11, -70MB amp).
__global__ __launch_bounds__(256) void pg_kernel(
    const int* __restrict__ src, const int* __restrict__ dst,
    int* __restrict__ gcurD, int* __restrict__ gcurS,
    int* __restrict__ gbufD, unsigned char* __restrict__ gbufS,
    const float* __restrict__ feat, const float* __restrict__ W1,
    unsigned short* __restrict__ h1, int E, int K, int PB, int N) {
    __shared__ char smem[16896];   // max(part 12.8 KB, gemm W1t 16.9 KB)
    const int t = threadIdx.x;

    if (blockIdx.x < PB) {
        // ---------------- part body ----------------
        int* cD = (int*)smem;
        int* bD = cD + 800;
        int* cS = bD + 800;
        int* bS = cS + 800;        // 3200 ints = 12.8 KB
        const int tile = blockIdx.x * TILE;
        const int vx = xcc_id();
        for (int i = t; i < K; i += 256) { cD[i] = 0; cS[i] = 0; }
        __syncthreads();

        int dv[32];
        #pragma unroll
        for (int i = 0; i < 32; ++i) {
            const int e = tile + i * 256 + t;
            dv[i] = (e < E) ? dst[e] : -1;
            if (dv[i] >= 0) {
                atomicAdd(&cD[dv[i] >> BSHIFT], 1);
                atomicAdd(&cS[src[e] >> BSHIFT], 1);
            }
        }
        __syncthreads();
        for (int i = t; i < K; i += 256) {
            int c = cD[i];
            bD[i] = (c ? atomicAdd(&gcurD[i], c) : 0) + i * CAP;
            cD[i] = 0;
            c = cS[i];
            bS[i] = (c ? atomicAdd(&gcurS[vx * K + i], c) : 0) + (vx * K + i) * CAPS;
            cS[i] = 0;
        }
        __syncthreads();
        #pragma unroll
        for (int i = 0; i < 32; ++i) {
            if (dv[i] >= 0) {
                const int e = tile + i * 256 + t;
                const int sv = src[e];
                const int b1 = dv[i] >> BSHIFT;
                const int p1 = bD[b1] + atomicAdd(&cD[b1], 1);
                gbufD[p1] = ((dv[i] & 127) << 17) | sv;
                const int b2 = sv >> BSHIFT;
                const int p2 = bS[b2] + atomicAdd(&cS[b2], 1);
                gbufS[p2] = (unsigned char)(sv & 127);
            }
        }
    } else {
        // ---------------- gemm1 body (unscaled h1) -------------------------
        short* W1t = (short*)smem;     // W1t[c][k] = bf16(W1[k][c]), stride 264
        for (int i = t; i < 8192; i += 256) {
            const int k = i >> 5, c = i & 31;
            W1t[c * 264 + k] = (short)f2bf(W1[i]);
        }
        __syncthreads();

        const int l  = t & 63;
        const int wv = t >> 6;
        const int base = (blockIdx.x - PB) * 128 + wv * 32;
        const int m  = l & 31;
        const int kh = (l >> 5) << 3;
        int r = base + m;
        if (r >= N) r = N - 1;
        const float* fr = feat + (size_t)r * 256 + kh;
        const short* wr = &W1t[m * 264 + kh];

        f32x16 acc;
        #pragma unroll
        for (int i = 0; i < 16; ++i) acc[i] = 0.f;

        #pragma unroll
        for (int kb = 0; kb < 16; ++kb) {
            const float4 f0 = *(const float4*)(fr + kb * 16);
            const float4 f1 = *(const float4*)(fr + kb * 16 + 4);
            bf16x8 a;
            a[0] = (short)f2bf(f0.x); a[1] = (short)f2bf(f0.y);
            a[2] = (short)f2bf(f0.z); a[3] = (short)f2bf(f0.w);
            a[4] = (short)f2bf(f1.x); a[5] = (short)f2bf(f1.y);
            a[6] = (short)f2bf(f1.z); a[7] = (short)f2bf(f1.w);
            const bf16x8 b = *(const bf16x8*)(wr + kb * 16);
            acc = __builtin_amdgcn_mfma_f32_32x32x16_bf16(a, b, acc, 0, 0, 0);
        }

        const int rbase = base + ((l >> 5) << 2);
        #pragma unroll
        for (int reg = 0; reg < 16; ++reg) {
            const int row = rbase + (reg & 3) + ((reg >> 2) << 3);
            if (row < N)
                h1[(size_t)row * 32 + m] = f2bf(acc[reg]);
        }
    }
}

// ---- fillS: outdeg -> nsrc, AND pre-scale this bucket's h1 rows by nsrc ---
__global__ __launch_bounds__(256) void fillS_kernel(
    const int* __restrict__ cntS, const unsigned char* __restrict__ gbufS,
    float* __restrict__ nsrc, unsigned* __restrict__ h1, int N, int K) {
    __shared__ int cnt[128];
    __shared__ float sns[128];
    const int t = threadIdx.x;
    const int b = blockIdx.x;
    if (t < 128) cnt[t] = 0;
    __syncthreads();
    for (int x = 0; x < NXCD; ++x) {
        const int seg = x * K + b;
        const int bs = seg * CAPS;
        const int be = bs + min(cntS[seg], CAPS);
        for (int idx = bs + t; idx < be; idx += 256)
            atomicAdd(&cnt[gbufS[idx]], 1);
    }
    __syncthreads();
    if (t < 128) {
        const float v = rsqrtf((float)cnt[t]);   // self-loops => deg>=1
        sns[t] = v;
        const int n = (b << BSHIFT) + t;
        if (n < N) nsrc[n] = v;
    }
    __syncthreads();
    // scale h1 rows in place: 2 threads/node x 8 u32 (row = 16 u32 = 64 B)
    const int node = t >> 1;
    const int n = (b << BSHIFT) + node;
    if (n < N) {
        const float ns = sns[node];
        unsigned* row = h1 + (size_t)n * 16 + (t & 1) * 8;
        uint4 q0 = *(uint4*)row;
        uint4 q1 = *(uint4*)(row + 4);
        q0.x = packbf2(bf_lo(q0.x) * ns, bf_hi(q0.x) * ns);
        q0.y = packbf2(bf_lo(q0.y) * ns, bf_hi(q0.y) * ns);
        q0.z = packbf2(bf_lo(q0.z) * ns, bf_hi(q0.z) * ns);
        q0.w = packbf2(bf_lo(q0.w) * ns, bf_hi(q0.w) * ns);
        q1.x = packbf2(bf_lo(q1.x) * ns, bf_hi(q1.x) * ns);
        q1.y = packbf2(bf_lo(q1.y) * ns, bf_hi(q1.y) * ns);
        q1.z = packbf2(bf_lo(q1.z) * ns, bf_hi(q1.z) * ns);
        q1.w = packbf2(bf_lo(q1.w) * ns, bf_hi(q1.w) * ns);
        *(uint4*)row = q0;
        *(uint4*)(row + 4) = q1;
    }
}

// ---- fda1: fillD + agg1 fused, one 512-thread block per dst-bucket --------
// R13: sort key = (dst<<2)|(src>>15) -- 512-way. Each node's CSR run is
// internally ordered by src-QUARTER (h1/x1s quarter <= 2MB, fits a per-XCD
// L2; whole buffer 6.4MB does not). All lanes/blocks stream quarter 0 -> 3
// together, so the gather working set is L2-resident instead of L3-served.
// agg2f inherits the same x1s blocking for free via the csr order.
__global__ __launch_bounds__(512) void fda1_kernel(
    const int* __restrict__ cntD, int* __restrict__ gbufD,
    const unsigned* __restrict__ h1, const float* __restrict__ nsrc,
    const float* __restrict__ b1, int* __restrict__ rowstart,
    int* __restrict__ indeg, float* __restrict__ ndst,
    unsigned* __restrict__ x1s, int N, int K) {
    __shared__ int lraw[CAP];          // 22.5 KB
    __shared__ int lcsr[CAP];          // 22.5 KB
    __shared__ int cnt[512], sc[512], cur[512];   // 6 KB (512-way: dst x quarter)
    __shared__ float sb1[32];
    const int t = threadIdx.x;
    const int b = blockIdx.x;
    if (t < 512) cnt[t] = 0;
    if (t < 32) sb1[t] = b1[t];
    __syncthreads();

    const int bs = b * CAP;
    const int total = min(cntD[b], CAP);   // defensive clamp (LDS bounds)
    for (int i = t; i < total; i += 512) {
        const int v = gbufD[bs + i];
        lraw[i] = v;
        const int key = ((v >> 17) << 2) | ((v & 131071) >> 15);  // dst*4+quarter
        atomicAdd(&cnt[key], 1);
    }
    __syncthreads();
    sc[t] = cnt[t];
    __syncthreads();
    for (int off = 1; off < 512; off <<= 1) {
        int x = (t >= off) ? sc[t - off] : 0;
        __syncthreads();
        sc[t] += x;
        __syncthreads();
    }
    cur[t] = sc[t] - cnt[t];
    if (t < 128) {
        const int rsl = sc[4 * t] - cnt[4 * t];
        const int deg = sc[4 * t + 3] - rsl;
        const int n = (b << BSHIFT) + t;
        if (n < N) {
            rowstart[n] = bs + rsl;
            indeg[n] = deg;
            ndst[n] = rsqrtf((float)max(deg, 1));   // self-loops => deg >= 1
        }
    }
    __syncthreads();
    for (int i = t; i < total; i += 512) {
        const int v = lraw[i];
        const int key = ((v >> 17) << 2) | ((v & 131071) >> 15);
        const int pos = atomicAdd(&cur[key], 1);
        lcsr[pos] = v & 131071;
    }
    __syncthreads();
    // dump sorted CSR for agg2f, in place over this bucket's gbufD segment
    for (int i = t; i < total; i += 512) gbufD[bs + i] = lcsr[i];

    // ---- agg1 from LDS csr: 8 lanes/node, 2 passes of 64 nodes ----
    const int c  = t & 3;
    const int eg = (t >> 2) & 1;
    const uint4* H = (const uint4*)h1;
    for (int half = 0; half < 2; ++half) {
        const int node = (t >> 3) + half * 64;
        const int n = (b << BSHIFT) + node;
        if (n >= N) continue;
        const int rs = sc[4 * node] - cnt[4 * node];
        const int re = sc[4 * node + 3];
        const int deg = re - rs;
        const int n8 = deg >> 3;
        float a0=0.f,a1=0.f,a2=0.f,a3=0.f,a4=0.f,a5=0.f,a6=0.f,a7=0.f;
        float d0=0.f,d1=0.f,d2=0.f,d3=0.f,d4=0.f,d5=0.f,d6=0.f,d7=0.f;
        for (int i = 0; i < n8; ++i) {
            const int k0 = rs + i * 8 + eg * 4;
            const int s0 = lcsr[k0],     s1 = lcsr[k0 + 1];
            const int s2 = lcsr[k0 + 2], s3 = lcsr[k0 + 3];
            const uint4 q0 = H[(size_t)s0 * 4 + c];
            const uint4 q1 = H[(size_t)s1 * 4 + c];
            const uint4 q2 = H[(size_t)s2 * 4 + c];
            const uint4 q3 = H[(size_t)s3 * 4 + c];
            a0 += bf_lo(q0.x); a1 += bf_hi(q0.x);
            a2 += bf_lo(q0.y); a3 += bf_hi(q0.y);
            a4 += bf_lo(q0.z); a5 += bf_hi(q0.z);
            a6 += bf_lo(q0.w); a7 += bf_hi(q0.w);
            d0 += bf_lo(q1.x); d1 += bf_hi(q1.x);
            d2 += bf_lo(q1.y); d3 += bf_hi(q1.y);
            d4 += bf_lo(q1.z); d5 += bf_hi(q1.z);
            d6 += bf_lo(q1.w); d7 += bf_hi(q1.w);
            a0 += bf_lo(q2.x); a1 += bf_hi(q2.x);
            a2 += bf_lo(q2.y); a3 += bf_hi(q2.y);
            a4 += bf_lo(q2.z); a5 += bf_hi(q2.z);
            a6 += bf_lo(q2.w); a7 += bf_hi(q2.w);
            d0 += bf_lo(q3.x); d1 += bf_hi(q3.x);
            d2 += bf_lo(q3.y); d3 += bf_hi(q3.y);
            d4 += bf_lo(q3.z); d5 += bf_hi(q3.z);
            d6 += bf_lo(q3.w); d7 += bf_hi(q3.w);
        }
        for (int k = rs + n8 * 8 + eg; k < re; k += 2) {
            const int s0 = lcsr[k];
            const uint4 q0 = H[(size_t)s0 * 4 + c];
            a0 += bf_lo(q0.x); a1 += bf_hi(q0.x);
            a2 += bf_lo(q0.y); a3 += bf_hi(q0.y);
            a4 += bf_lo(q0.z); a5 += bf_hi(q0.z);
            a6 += bf_lo(q0.w); a7 += bf_hi(q0.w);
        }
        a0 += d0; a1 += d1; a2 += d2; a3 += d3;
        a4 += d4; a5 += d5; a6 += d6; a7 += d7;
        // merge the two edge-groups (lanes t and t^4)
        a0 += __shfl_xor(a0, 4, 64); a1 += __shfl_xor(a1, 4, 64);
        a2 += __shfl_xor(a2, 4, 64); a3 += __shfl_xor(a3, 4, 64);
        a4 += __shfl_xor(a4, 4, 64); a5 += __shfl_xor(a5, 4, 64);
        a6 += __shfl_xor(a6, 4, 64); a7 += __shfl_xor(a7, 4, 64);
        if (eg == 0) {
            const float nd = rsqrtf((float)max(deg, 1));
            const float ns = nsrc[n];
            const float* bb = sb1 + c * 8;
            float x0 = fmaxf(a0 * nd + bb[0], 0.f) * ns;
            float x1 = fmaxf(a1 * nd + bb[1], 0.f) * ns;
            float x2 = fmaxf(a2 * nd + bb[2], 0.f) * ns;
            float x3 = fmaxf(a3 * nd + bb[3], 0.f) * ns;
            float x4 = fmaxf(a4 * nd + bb[4], 0.f) * ns;
            float x5 = fmaxf(a5 * nd + bb[5], 0.f) * ns;
            float x6 = fmaxf(a6 * nd + bb[6], 0.f) * ns;
            float x7 = fmaxf(a7 * nd + bb[7], 0.f) * ns;
            uint4 o;
            o.x = packbf2(x0, x1); o.y = packbf2(x2, x3);
            o.z = packbf2(x4, x5); o.w = packbf2(x6, x7);
            ((uint4*)x1s)[(size_t)n * 4 + c] = o;
        }
    }
}

// ---- agg2+final fused: 8 lanes/node edge-split, 32 nodes/block ------------
__global__ __launch_bounds__(256) void agg2f_kernel(
    const int* __restrict__ csr_src, const int* __restrict__ rowstart,
    const int* __restrict__ indeg, const unsigned* __restrict__ x1s,
    const float* __restrict__ ndst, const float* __restrict__ W2,
    const float* __restrict__ b2, float* __restrict__ out, int N) {
    __shared__ float sW2[32 * 40];
    __shared__ float sb2[40];
    const int t = threadIdx.x;
    for (int i = t; i < 1280; i += 256) sW2[i] = W2[i];
    if (t < 40) sb2[t] = b2[t];
    __syncthreads();
    const int n = blockIdx.x * 32 + (t >> 3);
    if (n >= N) return;
    const int c  = t & 3;
    const int eg = (t >> 2) & 1;
    const int rs = rowstart[n];
    const int deg = indeg[n];
    const int re = rs + deg;
    const int n8 = deg >> 3;
    float a0=0.f,a1=0.f,a2=0.f,a3=0.f,a4=0.f,a5=0.f,a6=0.f,a7=0.f;
    float d0=0.f,d1=0.f,d2=0.f,d3=0.f,d4=0.f,d5=0.f,d6=0.f,d7=0.f;
    const uint4* H = (const uint4*)x1s;
    for (int i = 0; i < n8; ++i) {
        const int k0 = rs + i * 8 + eg * 4;
        const int s0 = csr_src[k0],     s1 = csr_src[k0 + 1];
        const int s2 = csr_src[k0 + 2], s3 = csr_src[k0 + 3];
        const uint4 q0 = H[(size_t)s0 * 4 + c];
        const uint4 q1 = H[(size_t)s1 * 4 + c];
        const uint4 q2 = H[(size_t)s2 * 4 + c];
        const uint4 q3 = H[(size_t)s3 * 4 + c];
        a0 += bf_lo(q0.x); a1 += bf_hi(q0.x);
        a2 += bf_lo(q0.y); a3 += bf_hi(q0.y);
        a4 += bf_lo(q0.z); a5 += bf_hi(q0.z);
        a6 += bf_lo(q0.w); a7 += bf_hi(q0.w);
        d0 += bf_lo(q1.x); d1 += bf_hi(q1.x);
        d2 += bf_lo(q1.y); d3 += bf_hi(q1.y);
        d4 += bf_lo(q1.z); d5 += bf_hi(q1.z);
        d6 += bf_lo(q1.w); d7 += bf_hi(q1.w);
        a0 += bf_lo(q2.x); a1 += bf_hi(q2.x);
        a2 += bf_lo(q2.y); a3 += bf_hi(q2.y);
        a4 += bf_lo(q2.z); a5 += bf_hi(q2.z);
        a6 += bf_lo(q2.w); a7 += bf_hi(q2.w);
        d0 += bf_lo(q3.x); d1 += bf_hi(q3.x);
        d2 += bf_lo(q3.y); d3 += bf_hi(q3.y);
        d4 += bf_lo(q3.z); d5 += bf_hi(q3.z);
        d6 += bf_lo(q3.w); d7 += bf_hi(q3.w);
    }
    for (int k = rs + n8 * 8 + eg; k < re; k += 2) {
        const int s0 = csr_src[k];
        const uint4 q0 = H[(size_t)s0 * 4 + c];
        a0 += bf_lo(q0.x); a1 += bf_hi(q0.x);
        a2 += bf_lo(q0.y); a3 += bf_hi(q0.y);
        a4 += bf_lo(q0.z); a5 += bf_hi(q0.z);
        a6 += bf_lo(q0.w); a7 += bf_hi(q0.w);
    }
    a0 += d0; a1 += d1; a2 += d2; a3 += d3;
    a4 += d4; a5 += d5; a6 += d6; a7 += d7;
    a0 += __shfl_xor(a0, 4, 64); a1 += __shfl_xor(a1, 4, 64);
    a2 += __shfl_xor(a2, 4, 64); a3 += __shfl_xor(a3, 4, 64);
    a4 += __shfl_xor(a4, 4, 64); a5 += __shfl_xor(a5, 4, 64);
    a6 += __shfl_xor(a6, 4, 64); a7 += __shfl_xor(a7, 4, 64);
    const float nd = ndst[n];
    const float v0 = a0 * nd, v1 = a1 * nd, v2 = a2 * nd, v3 = a3 * nd;
    const float v4 = a4 * nd, v5 = a5 * nd, v6 = a6 * nd, v7 = a7 * nd;

    // lane j of the node's 8-lane group computes logits j*5 .. j*5+4.
    const int j = t & 7;
    float z[5];
    #pragma unroll
    for (int u = 0; u < 5; ++u) z[u] = sb2[j * 5 + u];
    const int gbase = (t & 63) & ~7;      // wave-lane base of this node's group
    #pragma unroll
    for (int cc = 0; cc < 4; ++cc) {
        const int sl = gbase + cc;        // lane holding channel-quarter cc
        const float w0 = __shfl(v0, sl, 64);
        const float w1 = __shfl(v1, sl, 64);
        const float w2 = __shfl(v2, sl, 64);
        const float w3 = __shfl(v3, sl, 64);
        const float w4 = __shfl(v4, sl, 64);
        const float w5 = __shfl(v5, sl, 64);
        const float w6 = __shfl(v6, sl, 64);
        const float w7 = __shfl(v7, sl, 64);
        const float* Wr = &sW2[(cc * 8) * 40 + j * 5];
        #pragma unroll
        for (int u = 0; u < 5; ++u) {
            z[u] += w0 * Wr[u]       + w1 * Wr[40 + u]  + w2 * Wr[80 + u]  + w3 * Wr[120 + u]
                  + w4 * Wr[160 + u] + w5 * Wr[200 + u] + w6 * Wr[240 + u] + w7 * Wr[280 + u];
        }
    }
    float m = z[0];
    #pragma unroll
    for (int u = 1; u < 5; ++u) m = fmaxf(m, z[u]);
    m = fmaxf(m, __shfl_xor(m, 1, 64));
    m = fmaxf(m, __shfl_xor(m, 2, 64));
    m = fmaxf(m, __shfl_xor(m, 4, 64));
    float s = 0.f;
    #pragma unroll
    for (int u = 0; u < 5; ++u) s += __expf(z[u] - m);
    s += __shfl_xor(s, 1, 64);
    s += __shfl_xor(s, 2, 64);
    s += __shfl_xor(s, 4, 64);
    const float ls = __logf(s);
    float* op = out + (size_t)n * 40 + j * 5;
    #pragma unroll
    for (int u = 0; u < 5; ++u) op[u] = z[u] - m - ls;
}

extern "C" void kernel_launch(void* const* d_in, const int* in_sizes, int n_in,
                              void* d_out, int out_size, void* d_ws, size_t ws_size,
                              hipStream_t stream) {
    const float* feat = (const float*)d_in[0];
    const int*   src  = (const int*)d_in[1];
    const int*   dst  = (const int*)d_in[2];
    const float* W1   = (const float*)d_in[3];
    const float* b1   = (const float*)d_in[4];
    const float* W2   = (const float*)d_in[5];
    const float* b2   = (const float*)d_in[6];
    float* out = (float*)d_out;

    const int N = in_sizes[0] / 256;   // 100000
    const int E = in_sizes[1];         // 3300000
    const int K = NBUCK(N);            // 782 buckets of 128 nodes

    // layout (R11 form). Overlays:
    //   csr_src == gbufD (in-place sorted CSR).
    //   gbufS (NXCD*K*CAPS = 12.76 MB) -> over dead a2 region (12.8 MB).
    //   h1, x1s fully dedicated.
    char* p = (char*)d_ws;
    float* nsrc = (float*)p;                 p += (size_t)N * 4;        // 400 KB
    float* ndst = (float*)p;                 p += (size_t)N * 4;
    unsigned* h1  = (unsigned*)p;            p += (size_t)N * 64;       // 6.4 MB
    unsigned* x1s = (unsigned*)p;            p += (size_t)N * 64;       // 6.4 MB
    char* a2dead = (char*)p;                 p += (size_t)N * 128;      // 12.8 MB
    int* rowstart = (int*)p;                 p += (size_t)N * 4;
    int* indeg_i  = (int*)p;                 p += (size_t)N * 4;
    int* gcurD    = (int*)p;                 p += 800 * 4;
    int* gcurS    = (int*)p;                 p += (size_t)NXCD * 800 * 4;
    int* gbufD    = (int*)p;                 p += (size_t)K * CAP * 4;  // 17.6 MB, becomes csr
    unsigned char* gbufS = (unsigned char*)a2dead;   // 12.76 MB over dead a2

    hipMemsetAsync(gcurD, 0, sizeof(int) * (800 + NXCD * 800), stream);

    const int PB = (E + TILE - 1) / TILE;      // 403 partition blocks
    const int GB = (N + 127) / 128;            // 782 gemm blocks

    pg_kernel<<<PB + GB, 256, 0, stream>>>(src, dst, gcurD, gcurS, gbufD, gbufS,
                                           feat, W1, (unsigned short*)h1, E, K, PB, N);
    fillS_kernel<<<K, 256, 0, stream>>>(gcurS, gbufS, nsrc, h1, N, K);
    fda1_kernel<<<K, 512, 0, stream>>>(gcurD, gbufD, h1, nsrc, b1,
                                       rowstart, indeg_i, ndst, x1s, N, K);
    agg2f_kernel<<<(N + 31) / 32, 256, 0, stream>>>(gbufD, rowstart, indeg_i, x1s, ndst, W2, b2, out, N);
}